// Round 8
// baseline (494.907 us; speedup 1.0000x reference)
//
#include <hip/hip_runtime.h>

typedef __attribute__((ext_vector_type(4))) float f32x4;
typedef __attribute__((ext_vector_type(8))) short short8;
typedef __attribute__((ext_vector_type(8))) unsigned short u16x8;
typedef __attribute__((ext_vector_type(4))) unsigned short u16x4;

#define D_MODEL 1024
#define NHEADS 16
#define T_SEQ 2048
#define M_TOT 4096   // B*T

__device__ __forceinline__ unsigned short f2bf(float f) {
    union { float f; unsigned int u; } v; v.f = f;
    return (unsigned short)((v.u + 0x7fffu + ((v.u >> 16) & 1u)) >> 16);
}

// ---- 16-lane group all-reduce at VALU speed (DPP), shfl fallback (proven in R5) ----
#if __has_builtin(__builtin_amdgcn_update_dpp)
#define DPP_STEP(v, ctrl, OP)                                              \
    {                                                                      \
        union { float f; int i; } a_, b_;                                  \
        a_.f = (v);                                                        \
        b_.i = __builtin_amdgcn_update_dpp(a_.i, a_.i, ctrl, 0xf, 0xf, false); \
        (v) = OP((v), b_.f);                                               \
    }
__device__ __forceinline__ float rowmax16(float v) {
    DPP_STEP(v, 0xB1, fmaxf); DPP_STEP(v, 0x4E, fmaxf);
    DPP_STEP(v, 0x141, fmaxf); DPP_STEP(v, 0x140, fmaxf);
    return v;
}
__device__ __forceinline__ float rowsum16(float v) {
    #define FADD_(a, b) ((a) + (b))
    DPP_STEP(v, 0xB1, FADD_); DPP_STEP(v, 0x4E, FADD_);
    DPP_STEP(v, 0x141, FADD_); DPP_STEP(v, 0x140, FADD_);
    #undef FADD_
    return v;
}
#else
__device__ __forceinline__ float rowmax16(float v) {
    for (int off = 8; off >= 1; off >>= 1) v = fmaxf(v, __shfl_xor(v, off));
    return v;
}
__device__ __forceinline__ float rowsum16(float v) {
    for (int off = 8; off >= 1; off >>= 1) v += __shfl_xor(v, off);
    return v;
}
#endif

// ---------------- convert x fp32 -> bf16 ----------------
__global__ __launch_bounds__(256) void convert_x_kernel(const float* __restrict__ X,
                                                        unsigned short* __restrict__ Xb) {
    const int i = (blockIdx.x * 256 + threadIdx.x) * 4;
    const float4 v = *(const float4*)(X + i);
    u16x4 r;
    r.x = f2bf(v.x); r.y = f2bf(v.y); r.z = f2bf(v.z); r.w = f2bf(v.w);
    *(u16x4*)(Xb + i) = r;
}

// ---------------- 4x W [k][n] fp32 -> Wt [n][k] bf16, batched over z ----------------
__global__ __launch_bounds__(256) void transpose_w_kernel(const float* __restrict__ W0,
                                                          const float* __restrict__ W1,
                                                          const float* __restrict__ W2,
                                                          const float* __restrict__ W3,
                                                          unsigned short* __restrict__ Wt0) {
    __shared__ float tile[64][65];
    const int z = blockIdx.z;
    const float* W = (z == 0) ? W0 : (z == 1) ? W1 : (z == 2) ? W2 : W3;
    unsigned short* Wt = Wt0 + (size_t)z * D_MODEL * D_MODEL;
    const int n0 = blockIdx.x * 64, k0 = blockIdx.y * 64;
    for (int i = threadIdx.x; i < 4096; i += 256) {
        const int r = i >> 6, c = i & 63;
        tile[r][c] = W[(size_t)(k0 + r) * D_MODEL + n0 + c];
    }
    __syncthreads();
    for (int i = threadIdx.x; i < 4096; i += 256) {
        const int r = i >> 6, c = i & 63;  // r: n-local, c: k-local
        Wt[(size_t)(n0 + r) * D_MODEL + k0 + c] = f2bf(tile[c][r]);
    }
}

// ---------------- GEMM: C = A[M][1024] @ W, with Wt[n][k] pre-transposed ----------------
// OUTMODE 0: fp32 row-major C (out projection)
// OUTMODE 1: z=0 Q (RoPE, pre-scaled 0.125), z=1 K (RoPE), z=2 V (transposed [bh][d][t])
#define TN_G 128
#define BK_G 32
#define BKP_G 36

template<int MI, int OUTMODE>
__global__ __launch_bounds__(256) void gemm_kernel(
    const unsigned short* __restrict__ A,
    const unsigned short* __restrict__ Bt0,
    void* __restrict__ Cout0,
    const float* __restrict__ cosp,
    const float* __restrict__ sinp)
{
    constexpr int TMc = MI * 32;
    constexpr int NA = (TMc * 4) / 256;
    __shared__ unsigned short sA[TMc * BKP_G];
    __shared__ unsigned short sB[TN_G * BKP_G];

    const int tid = threadIdx.x;
    const int wid = tid >> 6;
    const int lane = tid & 63;
    const int quad = lane >> 4;
    const int l16 = lane & 15;
    const int wm = wid >> 1, wn = wid & 1;
    const int m0 = blockIdx.x * TMc, n0 = blockIdx.y * TN_G;
    const int z = blockIdx.z;
    const unsigned short* Bt = Bt0 + (size_t)z * D_MODEL * D_MODEL;

    f32x4 acc[MI][4] = {};

    for (int k0 = 0; k0 < D_MODEL; k0 += BK_G) {
        u16x8 av[NA], bv[2];
        #pragma unroll
        for (int i = 0; i < NA; ++i) {
            const int c = tid + i * 256, r = c >> 2, sg = (c & 3) * 8;
            av[i] = *(const u16x8*)(A + (size_t)(m0 + r) * D_MODEL + k0 + sg);
        }
        #pragma unroll
        for (int i = 0; i < 2; ++i) {
            const int c = tid + i * 256, r = c >> 2, sg = (c & 3) * 8;
            bv[i] = *(const u16x8*)(Bt + (size_t)(n0 + r) * D_MODEL + k0 + sg);
        }
        __syncthreads();
        #pragma unroll
        for (int i = 0; i < NA; ++i) {
            const int c = tid + i * 256, r = c >> 2, sg = (c & 3) * 8;
            *(u16x8*)&sA[r * BKP_G + sg] = av[i];
        }
        #pragma unroll
        for (int i = 0; i < 2; ++i) {
            const int c = tid + i * 256, r = c >> 2, sg = (c & 3) * 8;
            *(u16x8*)&sB[r * BKP_G + sg] = bv[i];
        }
        __syncthreads();

        short8 af[MI], bf[4];
        #pragma unroll
        for (int i = 0; i < MI; ++i)
            af[i] = *(const short8*)&sA[(wm * (MI * 16) + i * 16 + l16) * BKP_G + quad * 8];
        #pragma unroll
        for (int i = 0; i < 4; ++i)
            bf[i] = *(const short8*)&sB[(wn * 64 + i * 16 + l16) * BKP_G + quad * 8];
        #pragma unroll
        for (int mi = 0; mi < MI; ++mi)
            #pragma unroll
            for (int ni = 0; ni < 4; ++ni)
                acc[mi][ni] = __builtin_amdgcn_mfma_f32_16x16x32_bf16(af[mi], bf[ni], acc[mi][ni], 0, 0, 0);
    }

    if constexpr (OUTMODE == 0) {
        float* C = (float*)Cout0;
        #pragma unroll
        for (int mi = 0; mi < MI; ++mi) {
            const int mb = m0 + wm * (MI * 16) + mi * 16 + quad * 4;
            #pragma unroll
            for (int ni = 0; ni < 4; ++ni) {
                const int n = n0 + wn * 64 + ni * 16 + l16;
                #pragma unroll
                for (int r = 0; r < 4; ++r)
                    C[(size_t)(mb + r) * D_MODEL + n] = acc[mi][ni][r];
            }
        }
    } else {
        unsigned short* O = (unsigned short*)Cout0 + (size_t)z * M_TOT * D_MODEL;
        const int h = (n0 + wn * 64) >> 6;   // each wave's 64 cols = exactly one head
        if (z == 2) {
            // V: write transposed Vt[bh][d][t], packed u16x4 over 4 consecutive t
            #pragma unroll
            for (int mi = 0; mi < MI; ++mi) {
                const int mb = m0 + wm * (MI * 16) + mi * 16 + quad * 4;
                const int b = mb >> 11, t = mb & (T_SEQ - 1);
                #pragma unroll
                for (int ni = 0; ni < 4; ++ni) {
                    const int d = ni * 16 + l16;
                    u16x4 pk;
                    #pragma unroll
                    for (int r = 0; r < 4; ++r) pk[r] = f2bf(acc[mi][ni][r]);
                    *(u16x4*)(O + ((size_t)(b * NHEADS + h) * 64 + d) * T_SEQ + t) = pk;
                }
            }
        } else {
            const float qs = (z == 0) ? 0.125f : 1.0f;   // fold 1/sqrt(64) into Q (exact in bf16)
            #pragma unroll
            for (int mi = 0; mi < MI; ++mi) {
                #pragma unroll
                for (int r = 0; r < 4; ++r) {
                    const int m = m0 + wm * (MI * 16) + mi * 16 + quad * 4 + r;
                    const int b = m >> 11, t = m & (T_SEQ - 1);
                    const size_t rowoff = ((size_t)(b * NHEADS + h) * T_SEQ + t) * 64;
                    #pragma unroll
                    for (int ni = 0; ni < 2; ++ni) {
                        const int d = ni * 16 + l16;           // 0..31
                        const float c = cosp[t * 32 + d], s = sinp[t * 32 + d];
                        const float x1 = acc[mi][ni][r], x2 = acc[mi][ni + 2][r];
                        O[rowoff + d]      = f2bf((x1 * c - x2 * s) * qs);
                        O[rowoff + d + 32] = f2bf((x1 * s + x2 * c) * qs);
                    }
                }
            }
        }
    }
}

// ---------------- flash attention (causal): barrier-free two-pass, UNPAIRED (occupancy) ----------------
// One 64-row q-tile per block (4 waves x 16 rows), grid 32x32 = 1024 blocks -> 4 blocks/CU
// resident (vs 2 paired in R7; occupancy was grid-limited at 17.6%). LPT: largest tiles
// (t=31, 32 kv-iters) dispatched first so variable work backfills. K/Vt fragments loaded
// directly global->register (64B lines fully consumed); only LDS = per-wave P roundtrip;
// ZERO __syncthreads.
#define LDP 68   // P LDS row pad (u16): scalar P writes conflict-free
#define LOG2E 1.44269504f

__global__ __launch_bounds__(256, 4) void attn_kernel(
    const unsigned short* __restrict__ Q,    // [bh][t][64] bf16, RoPE'd, pre-scaled 0.125
    const unsigned short* __restrict__ Kg,   // [bh][t][64] bf16, RoPE'd
    const unsigned short* __restrict__ Vt,   // [bh][d][t]  bf16 (transposed)
    unsigned short* __restrict__ Z)          // [m][h*64+d] bf16
{
    __shared__ unsigned short sP[4][16 * LDP];

    const int tid = threadIdx.x;
    const int wid = tid >> 6;
    const int lane = tid & 63;
    const int quad = lane >> 4;
    const int l16 = lane & 15;
    const int t = 31 - blockIdx.x;       // LPT: big tiles first
    const int bh = blockIdx.y;           // 0..31
    const int q0 = t * 64;
    const int jend = t;                  // kv tiles 0..t

    const unsigned short* Qp = Q + (size_t)bh * T_SEQ * 64;
    const unsigned short* Kp = Kg + (size_t)bh * T_SEQ * 64;
    const unsigned short* Vp = Vt + (size_t)bh * 64 * T_SEQ;

    // Q A-frags: row = q0 + wid*16 + l16, k = ks*32 + quad*8
    short8 aq[2];
    {
        const unsigned short* qr = Qp + (size_t)(q0 + wid * 16 + l16) * 64 + quad * 8;
        aq[0] = *(const short8*)(qr);
        aq[1] = *(const short8*)(qr + 32);
    }

    // direct-from-global fragment base addresses (per lane)
    const unsigned short* Kfb = Kp + (size_t)l16 * 64 + quad * 8;        // + (j*64+nt*16)*64 + ks*32
    const unsigned short* Vfb = Vp + (size_t)l16 * T_SEQ + quad * 8;     // + dt*16*T_SEQ + j*64 + ks*32

    auto qk_tile = [&](const short8 (&kf)[4][2], f32x4 (&s)[4]) {
        #pragma unroll
        for (int nt = 0; nt < 4; ++nt) {
            s[nt] = __builtin_amdgcn_mfma_f32_16x16x32_bf16(aq[0], kf[nt][0], s[nt], 0, 0, 0);
            s[nt] = __builtin_amdgcn_mfma_f32_16x16x32_bf16(aq[1], kf[nt][1], s[nt], 0, 0, 0);
        }
    };
    auto mask_tile = [&](f32x4 (&s)[4]) {   // causal mask on the diagonal 64x64 tile
        #pragma unroll
        for (int nt = 0; nt < 4; ++nt) {
            const int col = nt * 16 + l16;
            #pragma unroll
            for (int r = 0; r < 4; ++r) {
                const int row = wid * 16 + quad * 4 + r;
                if (col > row) s[nt][r] = -1e30f;
            }
        }
    };

    // ================= pass 1: exact row max (K only, register-only) =================
    float m_i[4] = {-1e30f, -1e30f, -1e30f, -1e30f};
    for (int j = 0; j <= jend; ++j) {
        short8 kf[4][2];
        #pragma unroll
        for (int nt = 0; nt < 4; ++nt)
            #pragma unroll
            for (int ks = 0; ks < 2; ++ks)
                kf[nt][ks] = *(const short8*)(Kfb + (size_t)(j * 64 + nt * 16) * 64 + ks * 32);
        f32x4 s[4] = {};
        qk_tile(kf, s);
        if (j == jend) mask_tile(s);
        #pragma unroll
        for (int r = 0; r < 4; ++r)
            m_i[r] = fmaxf(m_i[r], fmaxf(fmaxf(s[0][r], s[1][r]), fmaxf(s[2][r], s[3][r])));
    }
    float mL[4];
    #pragma unroll
    for (int r = 0; r < 4; ++r) mL[r] = rowmax16(m_i[r]) * LOG2E;

    // ================= pass 2: fixed-max softmax + PV (no loop-carried chain) =================
    f32x4 o[4] = {};
    float l_i[4] = {0.f, 0.f, 0.f, 0.f};
    unsigned short* Pw = &sP[wid][0];

    for (int j = 0; j <= jend; ++j) {
        short8 kf[4][2], vf[4][2];
        #pragma unroll
        for (int nt = 0; nt < 4; ++nt)
            #pragma unroll
            for (int ks = 0; ks < 2; ++ks) {
                kf[nt][ks] = *(const short8*)(Kfb + (size_t)(j * 64 + nt * 16) * 64 + ks * 32);
                vf[nt][ks] = *(const short8*)(Vfb + (size_t)(nt * 16) * T_SEQ + j * 64 + ks * 32);
            }

        f32x4 s[4] = {};
        qk_tile(kf, s);
        if (j == jend) mask_tile(s);

        #pragma unroll
        for (int nt = 0; nt < 4; ++nt) {
            const int col = nt * 16 + l16;
            #pragma unroll
            for (int r = 0; r < 4; ++r) {
                const float p = __builtin_exp2f(s[nt][r] * LOG2E - mL[r]);   // <= 1 always
                l_i[r] += p;
                Pw[(quad * 4 + r) * LDP + col] = f2bf(p);
            }
        }
        asm volatile("s_waitcnt lgkmcnt(0)" ::: "memory");

        const short8 pf0 = *(const short8*)&Pw[l16 * LDP + quad * 8];
        const short8 pf1 = *(const short8*)&Pw[l16 * LDP + 32 + quad * 8];

        #pragma unroll
        for (int dt = 0; dt < 4; ++dt) {
            o[dt] = __builtin_amdgcn_mfma_f32_16x16x32_bf16(pf0, vf[dt][0], o[dt], 0, 0, 0);
            o[dt] = __builtin_amdgcn_mfma_f32_16x16x32_bf16(pf1, vf[dt][1], o[dt], 0, 0, 0);
        }
        // no __syncthreads anywhere: sP is strictly per-wave
    }

    // single cross-lane row-sum of the per-lane l partials
    #pragma unroll
    for (int r = 0; r < 4; ++r) l_i[r] = 1.f / rowsum16(l_i[r]);

    // epilogue: normalize and write
    const int h = bh & 15, b = bh >> 4;
    #pragma unroll
    for (int dt = 0; dt < 4; ++dt)
        #pragma unroll
        for (int r = 0; r < 4; ++r) {
            const int row = q0 + wid * 16 + quad * 4 + r;
            const int col = h * 64 + dt * 16 + l16;
            Z[((size_t)b * T_SEQ + row) * D_MODEL + col] = f2bf(o[dt][r] * l_i[r]);
        }
}

// ---------------- launcher ----------------
extern "C" void kernel_launch(void* const* d_in, const int* in_sizes, int n_in,
                              void* d_out, int out_size, void* d_ws, size_t ws_size,
                              hipStream_t stream) {
    const float* x    = (const float*)d_in[0];
    const float* cosp = (const float*)d_in[1];
    const float* sinp = (const float*)d_in[2];
    const float* Wq   = (const float*)d_in[3];
    const float* Wk   = (const float*)d_in[4];
    const float* Wv   = (const float*)d_in[5];
    const float* Wo   = (const float*)d_in[6];

    char* w = (char*)d_ws;
    unsigned short* xb  = (unsigned short*)w; w += (size_t)M_TOT * D_MODEL * 2;    // 8 MB
    unsigned short* wt  = (unsigned short*)w; w += (size_t)4 * D_MODEL * D_MODEL * 2; // 8 MB (q,k,v,o)
    unsigned short* Qb  = (unsigned short*)w; w += (size_t)M_TOT * D_MODEL * 2;    // 8 MB
    unsigned short* Kb  = (unsigned short*)w; w += (size_t)M_TOT * D_MODEL * 2;
    unsigned short* Vtb = (unsigned short*)w; w += (size_t)M_TOT * D_MODEL * 2;    // [bh][d][t]
    unsigned short* Zb  = (unsigned short*)w; w += (size_t)M_TOT * D_MODEL * 2;

    convert_x_kernel<<<(M_TOT * D_MODEL) / 1024, 256, 0, stream>>>(x, xb);
    transpose_w_kernel<<<dim3(16, 16, 4), 256, 0, stream>>>(Wq, Wk, Wv, Wo, wt);

    // fused QKV projection; epilogue: z=0 Q(RoPE,*0.125), z=1 K(RoPE), z=2 V(transposed)
    gemm_kernel<4, 1><<<dim3(M_TOT / 128, D_MODEL / 128, 3), 256, 0, stream>>>(
        xb, wt, (void*)Qb, cosp, sinp);

    attn_kernel<<<dim3(32, 32), 256, 0, stream>>>(Qb, Kb, Vtb, Zb);

    // out projection -> fp32 d_out
    gemm_kernel<2, 0><<<dim3(M_TOT / 64, D_MODEL / 128, 1), 256, 0, stream>>>(
        Zb, wt + (size_t)3 * D_MODEL * D_MODEL, d_out, nullptr, nullptr);
}

// Round 9
// 280.660 us; speedup vs baseline: 1.7634x; 1.7634x over previous
//
#include <hip/hip_runtime.h>

typedef __attribute__((ext_vector_type(4))) float f32x4;
typedef __attribute__((ext_vector_type(8))) short short8;
typedef __attribute__((ext_vector_type(8))) unsigned short u16x8;
typedef __attribute__((ext_vector_type(4))) unsigned short u16x4;

#define D_MODEL 1024
#define NHEADS 16
#define T_SEQ 2048
#define M_TOT 4096   // B*T

__device__ __forceinline__ unsigned short f2bf(float f) {
    union { float f; unsigned int u; } v; v.f = f;
    return (unsigned short)((v.u + 0x7fffu + ((v.u >> 16) & 1u)) >> 16);
}
__device__ __forceinline__ float bf2f(unsigned short b) {
    union { unsigned int u; float f; } v; v.u = ((unsigned int)b) << 16;
    return v.f;
}

// ---- 16-lane group all-reduce at VALU speed (DPP), shfl fallback (proven R5) ----
#if __has_builtin(__builtin_amdgcn_update_dpp)
#define DPP_STEP(v, ctrl, OP)                                              \
    {                                                                      \
        union { float f; int i; } a_, b_;                                  \
        a_.f = (v);                                                        \
        b_.i = __builtin_amdgcn_update_dpp(a_.i, a_.i, ctrl, 0xf, 0xf, false); \
        (v) = OP((v), b_.f);                                               \
    }
__device__ __forceinline__ float rowsum16(float v) {
    #define FADD_(a, b) ((a) + (b))
    DPP_STEP(v, 0xB1, FADD_); DPP_STEP(v, 0x4E, FADD_);
    DPP_STEP(v, 0x141, FADD_); DPP_STEP(v, 0x140, FADD_);
    #undef FADD_
    return v;
}
#else
__device__ __forceinline__ float rowsum16(float v) {
    for (int off = 8; off >= 1; off >>= 1) v += __shfl_xor(v, off);
    return v;
}
#endif

// ---------------- convert x fp32 -> bf16 ----------------
__global__ __launch_bounds__(256) void convert_x_kernel(const float* __restrict__ X,
                                                        unsigned short* __restrict__ Xb) {
    const int i = (blockIdx.x * 256 + threadIdx.x) * 4;
    const float4 v = *(const float4*)(X + i);
    u16x4 r;
    r.x = f2bf(v.x); r.y = f2bf(v.y); r.z = f2bf(v.z); r.w = f2bf(v.w);
    *(u16x4*)(Xb + i) = r;
}

// ---------------- 4x W [k][n] fp32 -> Wt [n][k] bf16, batched over z ----------------
__global__ __launch_bounds__(256) void transpose_w_kernel(const float* __restrict__ W0,
                                                          const float* __restrict__ W1,
                                                          const float* __restrict__ W2,
                                                          const float* __restrict__ W3,
                                                          unsigned short* __restrict__ Wt0) {
    __shared__ float tile[64][65];
    const int z = blockIdx.z;
    const float* W = (z == 0) ? W0 : (z == 1) ? W1 : (z == 2) ? W2 : W3;
    unsigned short* Wt = Wt0 + (size_t)z * D_MODEL * D_MODEL;
    const int n0 = blockIdx.x * 64, k0 = blockIdx.y * 64;
    for (int i = threadIdx.x; i < 4096; i += 256) {
        const int r = i >> 6, c = i & 63;
        tile[r][c] = W[(size_t)(k0 + r) * D_MODEL + n0 + c];
    }
    __syncthreads();
    for (int i = threadIdx.x; i < 4096; i += 256) {
        const int r = i >> 6, c = i & 63;  // r: n-local, c: k-local
        Wt[(size_t)(n0 + r) * D_MODEL + k0 + c] = f2bf(tile[c][r]);
    }
}

// ---------------- GEMM: C = A[M][1024] @ W, with Wt[n][k] pre-transposed ----------------
#define TN_G 128
#define BK_G 32
#define BKP_G 36

template<int MI, int OUTMODE>
__global__ __launch_bounds__(256) void gemm_kernel(
    const unsigned short* __restrict__ A,
    const unsigned short* __restrict__ Bt0,
    void* __restrict__ Cout0,
    const float* __restrict__ cosp,
    const float* __restrict__ sinp)
{
    constexpr int TMc = MI * 32;
    constexpr int NA = (TMc * 4) / 256;
    __shared__ unsigned short sA[TMc * BKP_G];
    __shared__ unsigned short sB[TN_G * BKP_G];

    const int tid = threadIdx.x;
    const int wid = tid >> 6;
    const int lane = tid & 63;
    const int quad = lane >> 4;
    const int l16 = lane & 15;
    const int wm = wid >> 1, wn = wid & 1;
    const int m0 = blockIdx.x * TMc, n0 = blockIdx.y * TN_G;
    const int z = blockIdx.z;
    const unsigned short* Bt = Bt0 + (size_t)z * D_MODEL * D_MODEL;

    f32x4 acc[MI][4] = {};

    for (int k0 = 0; k0 < D_MODEL; k0 += BK_G) {
        u16x8 av[NA], bv[2];
        #pragma unroll
        for (int i = 0; i < NA; ++i) {
            const int c = tid + i * 256, r = c >> 2, sg = (c & 3) * 8;
            av[i] = *(const u16x8*)(A + (size_t)(m0 + r) * D_MODEL + k0 + sg);
        }
        #pragma unroll
        for (int i = 0; i < 2; ++i) {
            const int c = tid + i * 256, r = c >> 2, sg = (c & 3) * 8;
            bv[i] = *(const u16x8*)(Bt + (size_t)(n0 + r) * D_MODEL + k0 + sg);
        }
        __syncthreads();
        #pragma unroll
        for (int i = 0; i < NA; ++i) {
            const int c = tid + i * 256, r = c >> 2, sg = (c & 3) * 8;
            *(u16x8*)&sA[r * BKP_G + sg] = av[i];
        }
        #pragma unroll
        for (int i = 0; i < 2; ++i) {
            const int c = tid + i * 256, r = c >> 2, sg = (c & 3) * 8;
            *(u16x8*)&sB[r * BKP_G + sg] = bv[i];
        }
        __syncthreads();

        short8 af[MI], bf[4];
        #pragma unroll
        for (int i = 0; i < MI; ++i)
            af[i] = *(const short8*)&sA[(wm * (MI * 16) + i * 16 + l16) * BKP_G + quad * 8];
        #pragma unroll
        for (int i = 0; i < 4; ++i)
            bf[i] = *(const short8*)&sB[(wn * 64 + i * 16 + l16) * BKP_G + quad * 8];
        #pragma unroll
        for (int mi = 0; mi < MI; ++mi)
            #pragma unroll
            for (int ni = 0; ni < 4; ++ni)
                acc[mi][ni] = __builtin_amdgcn_mfma_f32_16x16x32_bf16(af[mi], bf[ni], acc[mi][ni], 0, 0, 0);
    }

    if constexpr (OUTMODE == 0) {
        float* C = (float*)Cout0;
        #pragma unroll
        for (int mi = 0; mi < MI; ++mi) {
            const int mb = m0 + wm * (MI * 16) + mi * 16 + quad * 4;
            #pragma unroll
            for (int ni = 0; ni < 4; ++ni) {
                const int n = n0 + wn * 64 + ni * 16 + l16;
                #pragma unroll
                for (int r = 0; r < 4; ++r)
                    C[(size_t)(mb + r) * D_MODEL + n] = acc[mi][ni][r];
            }
        }
    } else {
        unsigned short* O = (unsigned short*)Cout0 + (size_t)z * M_TOT * D_MODEL;
        const int h = (n0 + wn * 64) >> 6;   // each wave's 64 cols = exactly one head
        if (z == 2) {
            // V: write transposed Vt[bh][d][t], packed u16x4 over 4 consecutive t
            #pragma unroll
            for (int mi = 0; mi < MI; ++mi) {
                const int mb = m0 + wm * (MI * 16) + mi * 16 + quad * 4;
                const int b = mb >> 11, t = mb & (T_SEQ - 1);
                #pragma unroll
                for (int ni = 0; ni < 4; ++ni) {
                    const int d = ni * 16 + l16;
                    u16x4 pk;
                    #pragma unroll
                    for (int r = 0; r < 4; ++r) pk[r] = f2bf(acc[mi][ni][r]);
                    *(u16x4*)(O + ((size_t)(b * NHEADS + h) * 64 + d) * T_SEQ + t) = pk;
                }
            }
        } else {
            const float qs = (z == 0) ? 0.125f : 1.0f;   // fold 1/sqrt(64) into Q (exact in bf16)
            #pragma unroll
            for (int mi = 0; mi < MI; ++mi) {
                #pragma unroll
                for (int r = 0; r < 4; ++r) {
                    const int m = m0 + wm * (MI * 16) + mi * 16 + quad * 4 + r;
                    const int b = m >> 11, t = m & (T_SEQ - 1);
                    const size_t rowoff = ((size_t)(b * NHEADS + h) * T_SEQ + t) * 64;
                    #pragma unroll
                    for (int ni = 0; ni < 2; ++ni) {
                        const int d = ni * 16 + l16;           // 0..31
                        const float c = cosp[t * 32 + d], s = sinp[t * 32 + d];
                        const float x1 = acc[mi][ni][r], x2 = acc[mi][ni + 2][r];
                        O[rowoff + d]      = f2bf((x1 * c - x2 * s) * qs);
                        O[rowoff + d + 32] = f2bf((x1 * s + x2 * c) * qs);
                    }
                }
            }
        }
    }
}

// ---------------- K row-norm segment maxes: Kseg[bh][8] = max ||k_row|| over 256-row segs ----------------
__global__ __launch_bounds__(256) void kmax_kernel(const unsigned short* __restrict__ Kg,
                                                   float* __restrict__ Kseg) {
    __shared__ float red[4];
    const int seg = blockIdx.x, bh = blockIdx.y;
    const unsigned short* Kp = Kg + ((size_t)bh * T_SEQ + seg * 256) * 64;
    const int row = threadIdx.x;   // one row per thread
    const u16x8* rp = (const u16x8*)(Kp + (size_t)row * 64);
    float s = 0.f;
    #pragma unroll
    for (int c = 0; c < 8; ++c) {
        const u16x8 v = rp[c];
        #pragma unroll
        for (int e = 0; e < 8; ++e) { const float f = bf2f(v[e]); s += f * f; }
    }
    #pragma unroll
    for (int off = 32; off >= 1; off >>= 1) s = fmaxf(s, __shfl_xor(s, off));
    if ((threadIdx.x & 63) == 0) red[threadIdx.x >> 6] = s;
    __syncthreads();
    if (threadIdx.x == 0)
        Kseg[bh * 8 + seg] = __builtin_sqrtf(fmaxf(fmaxf(red[0], red[1]), fmaxf(red[2], red[3])));
}

// ---------------- flash attention (causal): SINGLE-PASS, Cauchy-Schwarz max bound ----------------
// m_hat = ||q_row|| * max_j ||k_j|| >= max s  (softmax shift-invariant -> exact math).
// p = exp2(s*log2e - m_hat*log2e) <= 1 structurally; underflow impossible (Delta <~ 16).
// R7's proven barrier-free paired structure, pass 1 deleted. No loop-carried anything.
#define LDP 68   // P LDS row pad (u16): scalar P writes conflict-free
#define LOG2E 1.44269504f

__global__ __launch_bounds__(256) void attn_kernel(
    const unsigned short* __restrict__ Q,    // [bh][t][64] bf16, RoPE'd, pre-scaled 0.125
    const unsigned short* __restrict__ Kg,   // [bh][t][64] bf16, RoPE'd
    const unsigned short* __restrict__ Vt,   // [bh][d][t]  bf16 (transposed)
    const float* __restrict__ Kseg,          // [bh][8] segment maxes of ||k||
    unsigned short* __restrict__ Z)          // [m][h*64+d] bf16
{
    __shared__ unsigned short sP[4][2][16 * LDP];

    const int tid = threadIdx.x;
    const int wid = tid >> 6;
    const int lane = tid & 63;
    const int quad = lane >> 4;
    const int l16 = lane & 15;
    const int x = blockIdx.x;            // 0..15
    const int bh = blockIdx.y;           // 0..31
    const int qA = x, qB = 31 - x;       // paired q-tiles: work = 32-x, near-uniform
    const int jend = 31 - x;             // kv tiles 0..jend cover both

    const unsigned short* Qp = Q + (size_t)bh * T_SEQ * 64;
    const unsigned short* Kp = Kg + (size_t)bh * T_SEQ * 64;
    const unsigned short* Vp = Vt + (size_t)bh * 64 * T_SEQ;

    // Q A-frags: row = qt*64 + wid*16 + l16, k = ks*32 + quad*8
    short8 aqA[2], aqB[2];
    {
        const unsigned short* qr = Qp + (size_t)(qA * 64 + wid * 16 + l16) * 64 + quad * 8;
        aqA[0] = *(const short8*)(qr);
        aqA[1] = *(const short8*)(qr + 32);
        qr = Qp + (size_t)(qB * 64 + wid * 16 + l16) * 64 + quad * 8;
        aqB[0] = *(const short8*)(qr);
        aqB[1] = *(const short8*)(qr + 32);
    }

    // ---- max bound m_hat (one-time): kmx = max ||k||; nq = ||q_row||^2 (A-layout),
    // gathered to C-layout rows (quad*4+r) via one bpermute ----
    float kmx = 0.f;
    #pragma unroll
    for (int i = 0; i < 8; ++i) kmx = fmaxf(kmx, Kseg[bh * 8 + i]);

    float mLA[4], mLB[4];
    {
        float nqA = 0.f, nqB = 0.f;
        #pragma unroll
        for (int i = 0; i < 2; ++i)
            #pragma unroll
            for (int e = 0; e < 8; ++e) {
                const float fa = bf2f((unsigned short)aqA[i][e]);
                const float fb = bf2f((unsigned short)aqB[i][e]);
                nqA += fa * fa; nqB += fb * fb;
            }
        nqA += __shfl_xor(nqA, 16); nqA += __shfl_xor(nqA, 32);
        nqB += __shfl_xor(nqB, 16); nqB += __shfl_xor(nqB, 32);
        #pragma unroll
        for (int r = 0; r < 4; ++r) {
            const int src = (lane & 48) | (quad * 4 + r);   // same-quad lane holding row quad*4+r
            mLA[r] = __builtin_sqrtf(__shfl(nqA, src)) * kmx * LOG2E;
            mLB[r] = __builtin_sqrtf(__shfl(nqB, src)) * kmx * LOG2E;
        }
    }

    // direct-from-global fragment base addresses (per lane)
    const unsigned short* Kfb = Kp + (size_t)l16 * 64 + quad * 8;
    const unsigned short* Vfb = Vp + (size_t)l16 * T_SEQ + quad * 8;

    auto mask_tile = [&](f32x4 (&s)[4]) {   // causal mask on the diagonal 64x64 tile
        #pragma unroll
        for (int nt = 0; nt < 4; ++nt) {
            const int col = nt * 16 + l16;
            #pragma unroll
            for (int r = 0; r < 4; ++r) {
                const int row = wid * 16 + quad * 4 + r;
                if (col > row) s[nt][r] = -1e30f;
            }
        }
    };
    auto tile_exp = [&](f32x4 (&s)[4], const float (&mL)[4], float (&l_i)[4], bool msk,
                        unsigned short* Pw) {
        if (msk) mask_tile(s);
        #pragma unroll
        for (int nt = 0; nt < 4; ++nt) {
            const int col = nt * 16 + l16;
            #pragma unroll
            for (int r = 0; r < 4; ++r) {
                const float p = __builtin_exp2f(s[nt][r] * LOG2E - mL[r]);   // <= 1 always
                l_i[r] += p;
                Pw[(quad * 4 + r) * LDP + col] = f2bf(p);
            }
        }
    };

    f32x4 oA[4] = {}, oB[4] = {};
    float lA[4] = {0.f, 0.f, 0.f, 0.f}, lB[4] = {0.f, 0.f, 0.f, 0.f};
    unsigned short* PwA = &sP[wid][0][0];
    unsigned short* PwB = &sP[wid][1][0];

    for (int j = 0; j <= jend; ++j) {
        const bool doA = (j <= x);

        short8 kf[4][2], vf[4][2];
        #pragma unroll
        for (int nt = 0; nt < 4; ++nt)
            #pragma unroll
            for (int ks = 0; ks < 2; ++ks) {
                kf[nt][ks] = *(const short8*)(Kfb + (size_t)(j * 64 + nt * 16) * 64 + ks * 32);
                vf[nt][ks] = *(const short8*)(Vfb + (size_t)(nt * 16) * T_SEQ + j * 64 + ks * 32);
            }

        f32x4 sAc[4] = {}, sBc[4] = {};
        #pragma unroll
        for (int nt = 0; nt < 4; ++nt) {
            if (doA) {
                sAc[nt] = __builtin_amdgcn_mfma_f32_16x16x32_bf16(aqA[0], kf[nt][0], sAc[nt], 0, 0, 0);
                sAc[nt] = __builtin_amdgcn_mfma_f32_16x16x32_bf16(aqA[1], kf[nt][1], sAc[nt], 0, 0, 0);
            }
            sBc[nt] = __builtin_amdgcn_mfma_f32_16x16x32_bf16(aqB[0], kf[nt][0], sBc[nt], 0, 0, 0);
            sBc[nt] = __builtin_amdgcn_mfma_f32_16x16x32_bf16(aqB[1], kf[nt][1], sBc[nt], 0, 0, 0);
        }

        if (doA) tile_exp(sAc, mLA, lA, j == x, PwA);
        tile_exp(sBc, mLB, lB, j == jend, PwB);
        asm volatile("s_waitcnt lgkmcnt(0)" ::: "memory");

        short8 pfA0 = {}, pfA1 = {}, pfB0, pfB1;
        if (doA) {
            pfA0 = *(const short8*)&PwA[l16 * LDP + quad * 8];
            pfA1 = *(const short8*)&PwA[l16 * LDP + 32 + quad * 8];
        }
        pfB0 = *(const short8*)&PwB[l16 * LDP + quad * 8];
        pfB1 = *(const short8*)&PwB[l16 * LDP + 32 + quad * 8];

        #pragma unroll
        for (int dt = 0; dt < 4; ++dt) {
            if (doA) {
                oA[dt] = __builtin_amdgcn_mfma_f32_16x16x32_bf16(pfA0, vf[dt][0], oA[dt], 0, 0, 0);
                oA[dt] = __builtin_amdgcn_mfma_f32_16x16x32_bf16(pfA1, vf[dt][1], oA[dt], 0, 0, 0);
            }
            oB[dt] = __builtin_amdgcn_mfma_f32_16x16x32_bf16(pfB0, vf[dt][0], oB[dt], 0, 0, 0);
            oB[dt] = __builtin_amdgcn_mfma_f32_16x16x32_bf16(pfB1, vf[dt][1], oB[dt], 0, 0, 0);
        }
        // no __syncthreads anywhere: sP is strictly per-wave
    }

    // single cross-lane row-sum of the per-lane l partials
    #pragma unroll
    for (int r = 0; r < 4; ++r) {
        lA[r] = 1.f / rowsum16(lA[r]);
        lB[r] = 1.f / rowsum16(lB[r]);
    }

    // epilogue: normalize and write
    const int h = bh & 15, b = bh >> 4;
    #pragma unroll
    for (int dt = 0; dt < 4; ++dt)
        #pragma unroll
        for (int r = 0; r < 4; ++r) {
            const int rowA = qA * 64 + wid * 16 + quad * 4 + r;
            const int rowB = qB * 64 + wid * 16 + quad * 4 + r;
            const int col = h * 64 + dt * 16 + l16;
            Z[((size_t)b * T_SEQ + rowA) * D_MODEL + col] = f2bf(oA[dt][r] * lA[r]);
            Z[((size_t)b * T_SEQ + rowB) * D_MODEL + col] = f2bf(oB[dt][r] * lB[r]);
        }
}

// ---------------- launcher ----------------
extern "C" void kernel_launch(void* const* d_in, const int* in_sizes, int n_in,
                              void* d_out, int out_size, void* d_ws, size_t ws_size,
                              hipStream_t stream) {
    const float* x    = (const float*)d_in[0];
    const float* cosp = (const float*)d_in[1];
    const float* sinp = (const float*)d_in[2];
    const float* Wq   = (const float*)d_in[3];
    const float* Wk   = (const float*)d_in[4];
    const float* Wv   = (const float*)d_in[5];
    const float* Wo   = (const float*)d_in[6];

    char* w = (char*)d_ws;
    unsigned short* xb  = (unsigned short*)w; w += (size_t)M_TOT * D_MODEL * 2;    // 8 MB
    unsigned short* wt  = (unsigned short*)w; w += (size_t)4 * D_MODEL * D_MODEL * 2; // 8 MB (q,k,v,o)
    unsigned short* Qb  = (unsigned short*)w; w += (size_t)M_TOT * D_MODEL * 2;    // 8 MB
    unsigned short* Kb  = (unsigned short*)w; w += (size_t)M_TOT * D_MODEL * 2;
    unsigned short* Vtb = (unsigned short*)w; w += (size_t)M_TOT * D_MODEL * 2;    // [bh][d][t]
    unsigned short* Zb  = (unsigned short*)w; w += (size_t)M_TOT * D_MODEL * 2;
    float*          Ks  = (float*)w;          w += 32 * 8 * sizeof(float);         // Kseg[bh][8]

    convert_x_kernel<<<(M_TOT * D_MODEL) / 1024, 256, 0, stream>>>(x, xb);
    transpose_w_kernel<<<dim3(16, 16, 4), 256, 0, stream>>>(Wq, Wk, Wv, Wo, wt);

    // fused QKV projection; epilogue: z=0 Q(RoPE,*0.125), z=1 K(RoPE), z=2 V(transposed)
    gemm_kernel<4, 1><<<dim3(M_TOT / 128, D_MODEL / 128, 3), 256, 0, stream>>>(
        xb, wt, (void*)Qb, cosp, sinp);

    kmax_kernel<<<dim3(8, 32), 256, 0, stream>>>(Kb, Ks);

    attn_kernel<<<dim3(16, 32), 256, 0, stream>>>(Qb, Kb, Vtb, Ks, Zb);

    // out projection -> fp32 d_out
    gemm_kernel<2, 0><<<dim3(M_TOT / 64, D_MODEL / 128, 1), 256, 0, stream>>>(
        Zb, wt + (size_t)3 * D_MODEL * D_MODEL, d_out, nullptr, nullptr);
}